// Round 3
// baseline (689.989 us; speedup 1.0000x reference)
//
#include <hip/hip_runtime.h>
#include <hip/hip_bf16.h>
#include <math.h>

#define CCH 256      // channels
#define MT  64       // points per block
#define ROWE 264     // padded LDS row (bf16 elems): 528 B stride = 132 dwords = 4 mod 32 banks
#define TPB 512

typedef __attribute__((ext_vector_type(8))) short short8;
typedef __attribute__((ext_vector_type(4))) float f32x4;

__device__ __forceinline__ unsigned short f2bf(float f) {
  unsigned u = __float_as_uint(f);
  u += 0x7fffu + ((u >> 16) & 1u);   // RNE; inputs are finite (post-relu)
  return (unsigned short)(u >> 16);
}
__device__ __forceinline__ float bf2f(unsigned short s) {
  return __uint_as_float(((unsigned)s) << 16);
}

// Transpose + bf16-convert the two 256x256 hidden weights: T[n*256+k] = bf16(W[k*256+n])
__global__ void transpose_w(const float* __restrict__ W0,
                            const float* __restrict__ W1,
                            unsigned short* __restrict__ T0,
                            unsigned short* __restrict__ T1) {
  __shared__ float tile[32][33];
  const float* src = blockIdx.z ? W1 : W0;
  unsigned short* dst = blockIdx.z ? T1 : T0;
  const int tx = threadIdx.x, ty = threadIdx.y;       // 32 x 8
  const int k0 = blockIdx.y * 32, n0 = blockIdx.x * 32;
#pragma unroll
  for (int r = 0; r < 4; ++r)
    tile[ty + r * 8][tx] = src[(k0 + ty + r * 8) * CCH + n0 + tx];
  __syncthreads();
#pragma unroll
  for (int r = 0; r < 4; ++r) {
    const int n = n0 + ty + r * 8;
    dst[n * CCH + k0 + tx] = f2bf(tile[tx][ty + r * 8]);
  }
}

// One hidden layer: dst = relu(src @ W + b), src/dst are [MT][ROWE] bf16 in LDS.
// Wave wv owns output cols [wv*32, wv*32+32). A-frags from LDS.
// TR=true : B-frags from transposed bf16 weights (contiguous 16B/lane, L2-hot).
// TR=false: fallback — strided fp32 W[k][n] loads + on-the-fly bf16 convert.
template <bool TR>
__device__ __forceinline__ void layer_gemm(
    const unsigned short (*__restrict__ src)[ROWE],
    unsigned short (*__restrict__ dst)[ROWE],
    const unsigned short* __restrict__ Wt,
    const float* __restrict__ Wraw,
    const float* __restrict__ bias,
    int wv, int l16, int lk8) {
  f32x4 acc[4][2];
#pragma unroll
  for (int mt = 0; mt < 4; ++mt)
#pragma unroll
    for (int nt = 0; nt < 2; ++nt)
      acc[mt][nt] = (f32x4){0.f, 0.f, 0.f, 0.f};

#pragma unroll
  for (int kk = 0; kk < 8; ++kk) {
    const int k = kk * 32 + lk8 * 8;                  // lane's 8 contiguous k
    short8 b0, b1;
    if constexpr (TR) {
      b0 = *(const short8*)&Wt[(wv * 32 + l16) * CCH + k];
      b1 = *(const short8*)&Wt[(wv * 32 + 16 + l16) * CCH + k];
    } else {
      const int n = wv * 32 + l16;
#pragma unroll
      for (int j = 0; j < 8; ++j) {
        b0[j] = (short)f2bf(Wraw[(k + j) * CCH + n]);
        b1[j] = (short)f2bf(Wraw[(k + j) * CCH + n + 16]);
      }
    }
#pragma unroll
    for (int mt = 0; mt < 4; ++mt) {
      const short8 a = *(const short8*)&src[mt * 16 + l16][k];
      acc[mt][0] = __builtin_amdgcn_mfma_f32_16x16x32_bf16(a, b0, acc[mt][0], 0, 0, 0);
      acc[mt][1] = __builtin_amdgcn_mfma_f32_16x16x32_bf16(a, b1, acc[mt][1], 0, 0, 0);
    }
  }

  // epilogue: bias + relu + bf16, C/D layout: col=lane&15, row=(lane>>4)*4+i
#pragma unroll
  for (int nt = 0; nt < 2; ++nt) {
    const int n = wv * 32 + nt * 16 + l16;
    const float bv = bias[n];
#pragma unroll
    for (int mt = 0; mt < 4; ++mt) {
#pragma unroll
      for (int i = 0; i < 4; ++i) {
        const int m = mt * 16 + lk8 * 4 + i;
        dst[m][n] = f2bf(fmaxf(acc[mt][nt][i] + bv, 0.0f));
      }
    }
  }
}

template <bool TR>
__global__ __launch_bounds__(TPB, 4) void nerf_fused(
    const float* __restrict__ uv,
    const float* __restrict__ W_in, const float* __restrict__ b_in,
    const float* __restrict__ W_h0r, const float* __restrict__ b_h0,
    const float* __restrict__ W_h1r, const float* __restrict__ b_h1,
    const float* __restrict__ W_out, const float* __restrict__ b_out,
    const unsigned short* __restrict__ T0,
    const unsigned short* __restrict__ T1,
    float* __restrict__ out) {
  __shared__ unsigned short hA[MT][ROWE];
  __shared__ unsigned short hB[MT][ROWE];
  __shared__ float wout_s[CCH * 3];
  __shared__ float bout_s[3];

  const int tid = threadIdx.x;
  const long n0 = (long)blockIdx.x * MT;

  // stage tiny output-layer weights
  for (int i = tid; i < CCH * 3; i += TPB) wout_s[i] = W_out[i];
  if (tid < 3) bout_s[tid] = b_out[tid];

  { // ---- layer 0: enc=[cos u, cos v, sin u, sin v] -> relu(enc@W_in+b_in) ----
    const int p = tid >> 3;            // 0..63
    const int c0 = (tid & 7) * 32;     // 32 channels per thread
    const float u = uv[(n0 + p) * 2 + 0];
    const float v = uv[(n0 + p) * 2 + 1];
    const float e0 = __cosf(u), e1 = __cosf(v), e2 = __sinf(u), e3 = __sinf(v);
#pragma unroll
    for (int i = 0; i < 32; i += 2) {
      const int c = c0 + i;
      float x0 = b_in[c] + e0 * W_in[c] + e1 * W_in[CCH + c] +
                 e2 * W_in[2 * CCH + c] + e3 * W_in[3 * CCH + c];
      float x1 = b_in[c + 1] + e0 * W_in[c + 1] + e1 * W_in[CCH + c + 1] +
                 e2 * W_in[2 * CCH + c + 1] + e3 * W_in[3 * CCH + c + 1];
      const unsigned pk = (unsigned)f2bf(fmaxf(x0, 0.f)) |
                          ((unsigned)f2bf(fmaxf(x1, 0.f)) << 16);
      *(unsigned*)&hA[p][c] = pk;
    }
  }
  __syncthreads();

  const int wv = tid >> 6, ln = tid & 63;
  const int l16 = ln & 15, lk8 = ln >> 4;

  layer_gemm<TR>(hA, hB, T0, W_h0r, b_h0, wv, l16, lk8);   // h0 -> h1
  __syncthreads();
  layer_gemm<TR>(hB, hA, T1, W_h1r, b_h1, wv, l16, lk8);   // h1 -> h2
  __syncthreads();

  { // ---- output layer: sigmoid(h2 @ W_out + b_out), 3 cols ----
    const int p = tid >> 3, g = tid & 7;        // 8 lanes share a point
    float s0 = 0.f, s1 = 0.f, s2 = 0.f;
#pragma unroll
    for (int kb = 0; kb < 4; ++kb) {
      const short8 hv = *(const short8*)&hA[p][g * 32 + kb * 8];
#pragma unroll
      for (int j = 0; j < 8; ++j) {
        const float h = bf2f((unsigned short)hv[j]);
        const int k = g * 32 + kb * 8 + j;
        s0 += h * wout_s[k * 3 + 0];
        s1 += h * wout_s[k * 3 + 1];
        s2 += h * wout_s[k * 3 + 2];
      }
    }
#pragma unroll
    for (int d = 1; d < 8; d <<= 1) {   // reduce over the 8 k-slices
      s0 += __shfl_xor(s0, d);
      s1 += __shfl_xor(s1, d);
      s2 += __shfl_xor(s2, d);
    }
    if (g == 0) {
      out[(n0 + p) * 3 + 0] = 1.f / (1.f + __expf(-(s0 + bout_s[0])));
      out[(n0 + p) * 3 + 1] = 1.f / (1.f + __expf(-(s1 + bout_s[1])));
      out[(n0 + p) * 3 + 2] = 1.f / (1.f + __expf(-(s2 + bout_s[2])));
    }
  }
}

extern "C" void kernel_launch(void* const* d_in, const int* in_sizes, int n_in,
                              void* d_out, int out_size, void* d_ws, size_t ws_size,
                              hipStream_t stream) {
  const float* uv    = (const float*)d_in[0];
  const float* W_in  = (const float*)d_in[1];
  const float* b_in  = (const float*)d_in[2];
  const float* W_h0  = (const float*)d_in[3];
  const float* b_h0  = (const float*)d_in[4];
  const float* W_h1  = (const float*)d_in[5];
  const float* b_h1  = (const float*)d_in[6];
  const float* W_out = (const float*)d_in[7];
  const float* b_out = (const float*)d_in[8];

  const int N = in_sizes[0] / 2;                    // 524288
  const size_t t_bytes = (size_t)2 * CCH * CCH * sizeof(unsigned short);  // 256 KiB

  if (ws_size >= t_bytes) {
    unsigned short* T0 = (unsigned short*)d_ws;     // 256*256 bf16
    unsigned short* T1 = T0 + CCH * CCH;
    transpose_w<<<dim3(8, 8, 2), dim3(32, 8), 0, stream>>>(W_h0, W_h1, T0, T1);
    nerf_fused<true><<<dim3(N / MT), dim3(TPB), 0, stream>>>(
        uv, W_in, b_in, W_h0, b_h0, W_h1, b_h1, W_out, b_out, T0, T1,
        (float*)d_out);
  } else {
    nerf_fused<false><<<dim3(N / MT), dim3(TPB), 0, stream>>>(
        uv, W_in, b_in, W_h0, b_h0, W_h1, b_h1, W_out, b_out,
        (const unsigned short*)nullptr, (const unsigned short*)nullptr,
        (float*)d_out);
  }
}

// Round 5
// 521.942 us; speedup vs baseline: 1.3220x; 1.3220x over previous
//
#include <hip/hip_runtime.h>
#include <hip/hip_bf16.h>
#include <math.h>

#define CCH 256      // channels
#define MT  64       // points per block
#define ROWE 264     // padded LDS row (bf16): 528 B stride = 132 dwords = 4 mod 32 banks
#define TPB 512

typedef __attribute__((ext_vector_type(8))) short short8;
typedef __attribute__((ext_vector_type(4))) short short4v;
typedef __attribute__((ext_vector_type(4))) float f32x4;
typedef __attribute__((ext_vector_type(2))) float f32x2;

__device__ __forceinline__ unsigned short f2bf(float f) {
  unsigned u = __float_as_uint(f);
  u += 0x7fffu + ((u >> 16) & 1u);   // RNE; inputs finite
  return (unsigned short)(u >> 16);
}
__device__ __forceinline__ float bf2f(unsigned short s) {
  return __uint_as_float(((unsigned)s) << 16);
}

// Transpose + bf16-convert the two 256x256 hidden weights: T[n*256+k] = bf16(W[k*256+n])
__global__ void transpose_w(const float* __restrict__ W0,
                            const float* __restrict__ W1,
                            unsigned short* __restrict__ T0,
                            unsigned short* __restrict__ T1) {
  __shared__ float tile[32][33];
  const float* src = blockIdx.z ? W1 : W0;
  unsigned short* dst = blockIdx.z ? T1 : T0;
  const int tx = threadIdx.x, ty = threadIdx.y;       // 32 x 8
  const int k0 = blockIdx.y * 32, n0 = blockIdx.x * 32;
#pragma unroll
  for (int r = 0; r < 4; ++r)
    tile[ty + r * 8][tx] = src[(k0 + ty + r * 8) * CCH + n0 + tx];
  __syncthreads();
#pragma unroll
  for (int r = 0; r < 4; ++r) {
    const int n = n0 + ty + r * 8;
    dst[n * CCH + k0 + tx] = f2bf(tile[tx][ty + r * 8]);
  }
}

// Prefetch one layer's weight fragments for this wave's 32 output channels.
// w[nt][kk]: channel col = wv*32 + nt*16 + l16, k = kk*32 + lk8*8 (.. +8)
template <bool TR>
__device__ __forceinline__ void load_w(short8 w[2][8],
                                       const unsigned short* __restrict__ Wt,
                                       const float* __restrict__ Wraw,
                                       int wv, int l16, int lk8) {
#pragma unroll
  for (int kk = 0; kk < 8; ++kk) {
    const int k = kk * 32 + lk8 * 8;
    if constexpr (TR) {
      w[0][kk] = *(const short8*)&Wt[(wv * 32 + l16) * CCH + k];
      w[1][kk] = *(const short8*)&Wt[(wv * 32 + 16 + l16) * CCH + k];
    } else {
      const int n = wv * 32 + l16;
#pragma unroll
      for (int j = 0; j < 8; ++j) {
        w[0][kk][j] = (short)f2bf(Wraw[(k + j) * CCH + n]);
        w[1][kk][j] = (short)f2bf(Wraw[(k + j) * CCH + n + 16]);
      }
    }
  }
}

// dst = relu(src @ W + b) using SWAPPED mfma operands: D = W^T * h^T so each
// lane holds 4 CONSECUTIVE channels of one point -> aligned b64 LDS writes.
__device__ __forceinline__ void layer_mfma(
    const unsigned short (*__restrict__ src)[ROWE],
    unsigned short (*__restrict__ dst)[ROWE],
    const short8 w[2][8],
    const float* __restrict__ bias,
    int wv, int l16, int lk8) {
  f32x4 acc[4][2];
#pragma unroll
  for (int mt = 0; mt < 4; ++mt)
#pragma unroll
    for (int nt = 0; nt < 2; ++nt)
      acc[mt][nt] = (f32x4){0.f, 0.f, 0.f, 0.f};

#pragma unroll
  for (int kk = 0; kk < 8; ++kk) {
    const int k = kk * 32 + lk8 * 8;
#pragma unroll
    for (int mt = 0; mt < 4; ++mt) {
      const short8 a = *(const short8*)&src[mt * 16 + l16][k];
      acc[mt][0] = __builtin_amdgcn_mfma_f32_16x16x32_bf16(w[0][kk], a, acc[mt][0], 0, 0, 0);
      acc[mt][1] = __builtin_amdgcn_mfma_f32_16x16x32_bf16(w[1][kk], a, acc[mt][1], 0, 0, 0);
    }
  }

  // D[ch][pt]: pt = mt*16 + l16 (col=lane&15), ch = wv*32 + nt*16 + lk8*4 + i
#pragma unroll
  for (int nt = 0; nt < 2; ++nt) {
    const int ch0 = wv * 32 + nt * 16 + lk8 * 4;
    const f32x4 bv = *(const f32x4*)&bias[ch0];
#pragma unroll
    for (int mt = 0; mt < 4; ++mt) {
      const int pt = mt * 16 + l16;
      short4v pk;
#pragma unroll
      for (int i = 0; i < 4; ++i)
        pk[i] = (short)f2bf(fmaxf(acc[mt][nt][i] + bv[i], 0.0f));
      *(short4v*)&dst[pt][ch0] = pk;   // 8B aligned: 528 and 2*ch0 both %8==0
    }
  }
}

template <bool TR>
__global__ __launch_bounds__(TPB, 4) void nerf_fused(
    const float* __restrict__ uv,
    const float* __restrict__ W_in, const float* __restrict__ b_in,
    const float* __restrict__ W_h0r, const float* __restrict__ b_h0,
    const float* __restrict__ W_h1r, const float* __restrict__ b_h1,
    const float* __restrict__ W_out, const float* __restrict__ b_out,
    const unsigned short* __restrict__ T0,
    const unsigned short* __restrict__ T1,
    float* __restrict__ out) {
  __shared__ unsigned short hA[MT][ROWE];
  __shared__ unsigned short hB[MT][ROWE];
  __shared__ float wout_s[CCH * 3];
  __shared__ float bout_s[3];

  const int tid = threadIdx.x;
  const long n0 = (long)blockIdx.x * MT;
  const int wv = tid >> 6, ln = tid & 63;
  const int l16 = ln & 15, lk8 = ln >> 4;

  // issue gemm0 weight prefetch FIRST: L2 latency hides under layer 0
  short8 w[2][8];
  load_w<TR>(w, T0, W_h0r, wv, l16, lk8);

  // stage tiny output-layer weights
  for (int i = tid; i < CCH * 3; i += TPB) wout_s[i] = W_out[i];
  if (tid < 3) bout_s[tid] = b_out[tid];

  { // ---- layer 0: enc=[cos u, cos v, sin u, sin v] -> relu(enc@W_in+b_in)
    // channel map c = 2*(tid&7) + 16*j: LDS banks 4p+(t7)+8j -> 2-way (free)
    const int p = tid >> 3;
    const int t7 = tid & 7;
    const float u = uv[(n0 + p) * 2 + 0];
    const float v = uv[(n0 + p) * 2 + 1];
    const float e0 = __cosf(u), e1 = __cosf(v), e2 = __sinf(u), e3 = __sinf(v);
#pragma unroll
    for (int j = 0; j < 16; ++j) {
      const int c = t7 * 2 + j * 16;
      const f32x2 w0 = *(const f32x2*)&W_in[0 * CCH + c];
      const f32x2 w1 = *(const f32x2*)&W_in[1 * CCH + c];
      const f32x2 w2 = *(const f32x2*)&W_in[2 * CCH + c];
      const f32x2 w3 = *(const f32x2*)&W_in[3 * CCH + c];
      const f32x2 bb = *(const f32x2*)&b_in[c];
      const float x0 = bb[0] + e0 * w0[0] + e1 * w1[0] + e2 * w2[0] + e3 * w3[0];
      const float x1 = bb[1] + e0 * w0[1] + e1 * w1[1] + e2 * w2[1] + e3 * w3[1];
      const unsigned pk = (unsigned)f2bf(fmaxf(x0, 0.f)) |
                          ((unsigned)f2bf(fmaxf(x1, 0.f)) << 16);
      *(unsigned*)&hA[p][c] = pk;
    }
  }
  __syncthreads();

  layer_mfma(hA, hB, w, b_h0, wv, l16, lk8);      // h0 -> h1 (consumes w)
  load_w<TR>(w, T1, W_h1r, wv, l16, lk8);         // in flight across sync
  __syncthreads();
  layer_mfma(hB, hA, w, b_h1, wv, l16, lk8);      // h1 -> h2
  __syncthreads();

  { // ---- output layer: sigmoid(h2 @ W_out + b_out), 3 cols ----
    const int p = tid >> 3, g = tid & 7;          // 8 lanes share a point
    float s0 = 0.f, s1 = 0.f, s2 = 0.f;
#pragma unroll
    for (int kb = 0; kb < 4; ++kb) {
      const short8 hv = *(const short8*)&hA[p][g * 32 + kb * 8];
#pragma unroll
      for (int j = 0; j < 8; ++j) {
        const float h = bf2f((unsigned short)hv[j]);
        const int k = g * 32 + kb * 8 + j;
        s0 += h * wout_s[k * 3 + 0];
        s1 += h * wout_s[k * 3 + 1];
        s2 += h * wout_s[k * 3 + 2];
      }
    }
#pragma unroll
    for (int d = 1; d < 8; d <<= 1) {
      s0 += __shfl_xor(s0, d);
      s1 += __shfl_xor(s1, d);
      s2 += __shfl_xor(s2, d);
    }
    if (g == 0) {
      out[(n0 + p) * 3 + 0] = 1.f / (1.f + __expf(-(s0 + bout_s[0])));
      out[(n0 + p) * 3 + 1] = 1.f / (1.f + __expf(-(s1 + bout_s[1])));
      out[(n0 + p) * 3 + 2] = 1.f / (1.f + __expf(-(s2 + bout_s[2])));
    }
  }
}

extern "C" void kernel_launch(void* const* d_in, const int* in_sizes, int n_in,
                              void* d_out, int out_size, void* d_ws, size_t ws_size,
                              hipStream_t stream) {
  const float* uv    = (const float*)d_in[0];
  const float* W_in  = (const float*)d_in[1];
  const float* b_in  = (const float*)d_in[2];
  const float* W_h0  = (const float*)d_in[3];
  const float* b_h0  = (const float*)d_in[4];
  const float* W_h1  = (const float*)d_in[5];
  const float* b_h1  = (const float*)d_in[6];
  const float* W_out = (const float*)d_in[7];
  const float* b_out = (const float*)d_in[8];

  const int N = in_sizes[0] / 2;                    // 524288
  const size_t t_bytes = (size_t)2 * CCH * CCH * sizeof(unsigned short);  // 256 KiB

  if (ws_size >= t_bytes) {
    unsigned short* T0 = (unsigned short*)d_ws;     // 256*256 bf16
    unsigned short* T1 = T0 + CCH * CCH;
    transpose_w<<<dim3(8, 8, 2), dim3(32, 8), 0, stream>>>(W_h0, W_h1, T0, T1);
    nerf_fused<true><<<dim3(N / MT), dim3(TPB), 0, stream>>>(
        uv, W_in, b_in, W_h0, b_h0, W_h1, b_h1, W_out, b_out, T0, T1,
        (float*)d_out);
  } else {
    nerf_fused<false><<<dim3(N / MT), dim3(TPB), 0, stream>>>(
        uv, W_in, b_in, W_h0, b_h0, W_h1, b_h1, W_out, b_out,
        (const unsigned short*)nullptr, (const unsigned short*)nullptr,
        (float*)d_out);
  }
}

// Round 7
// 420.332 us; speedup vs baseline: 1.6415x; 1.2417x over previous
//
#include <hip/hip_runtime.h>
#include <hip/hip_bf16.h>
#include <math.h>

#define CCH 256      // channels
#define MT  64       // points per block
#define ROWE 264     // padded LDS row (bf16): 528 B stride = 132 dwords = 4 mod 32 banks
#define TPB 512

typedef __attribute__((ext_vector_type(8))) short short8;
typedef __attribute__((ext_vector_type(4))) short short4v;
typedef __attribute__((ext_vector_type(4))) float f32x4;

__device__ __forceinline__ unsigned short f2bf(float f) {
  unsigned u = __float_as_uint(f);
  u += 0x7fffu + ((u >> 16) & 1u);   // RNE; inputs finite
  return (unsigned short)(u >> 16);
}

// Transpose + bf16-convert the two 256x256 hidden weights: T[n*256+k] = bf16(W[k*256+n])
__global__ void transpose_w(const float* __restrict__ W0,
                            const float* __restrict__ W1,
                            unsigned short* __restrict__ T0,
                            unsigned short* __restrict__ T1) {
  __shared__ float tile[32][33];
  const float* src = blockIdx.z ? W1 : W0;
  unsigned short* dst = blockIdx.z ? T1 : T0;
  const int tx = threadIdx.x, ty = threadIdx.y;       // 32 x 8
  const int k0 = blockIdx.y * 32, n0 = blockIdx.x * 32;
#pragma unroll
  for (int r = 0; r < 4; ++r)
    tile[ty + r * 8][tx] = src[(k0 + ty + r * 8) * CCH + n0 + tx];
  __syncthreads();
#pragma unroll
  for (int r = 0; r < 4; ++r) {
    const int n = n0 + ty + r * 8;
    dst[n * CCH + k0 + tx] = f2bf(tile[tx][ty + r * 8]);
  }
}

// Wo_t[16][256] bf16, zero-padded: Wo_t[j][k] = W_out[k*3+j] for j<3 else 0
__global__ void prep_wo(const float* __restrict__ W_out,
                        unsigned short* __restrict__ Wo_t) {
  const int k = threadIdx.x;   // 256 threads
#pragma unroll
  for (int j = 0; j < 16; ++j)
    Wo_t[j * CCH + k] = (j < 3) ? f2bf(W_out[k * 3 + j]) : (unsigned short)0;
}

// Prefetch one layer's weight fragments for this wave's 32 output channels.
template <bool TR>
__device__ __forceinline__ void load_w(short8 w[2][8],
                                       const unsigned short* __restrict__ Wt,
                                       const float* __restrict__ Wraw,
                                       int wv, int l16, int lk8) {
#pragma unroll
  for (int kk = 0; kk < 8; ++kk) {
    const int k = kk * 32 + lk8 * 8;
    if constexpr (TR) {
      w[0][kk] = *(const short8*)&Wt[(wv * 32 + l16) * CCH + k];
      w[1][kk] = *(const short8*)&Wt[(wv * 32 + 16 + l16) * CCH + k];
    } else {
      const int n = wv * 32 + l16;
#pragma unroll
      for (int j = 0; j < 8; ++j) {
        w[0][kk][j] = (short)f2bf(Wraw[(k + j) * CCH + n]);
        w[1][kk][j] = (short)f2bf(Wraw[(k + j) * CCH + n + 16]);
      }
    }
  }
}

// dst = relu(src @ W + b), SWAPPED mfma operands: lane holds 4 consecutive
// channels of one point -> aligned b64 LDS writes.
__device__ __forceinline__ void layer_mfma(
    const unsigned short (*__restrict__ src)[ROWE],
    unsigned short (*__restrict__ dst)[ROWE],
    const short8 w[2][8],
    const float* __restrict__ bias,
    int wv, int l16, int lk8) {
  f32x4 acc[4][2];
#pragma unroll
  for (int mt = 0; mt < 4; ++mt)
#pragma unroll
    for (int nt = 0; nt < 2; ++nt)
      acc[mt][nt] = (f32x4){0.f, 0.f, 0.f, 0.f};

#pragma unroll
  for (int kk = 0; kk < 8; ++kk) {
    const int k = kk * 32 + lk8 * 8;
#pragma unroll
    for (int mt = 0; mt < 4; ++mt) {
      const short8 a = *(const short8*)&src[mt * 16 + l16][k];
      acc[mt][0] = __builtin_amdgcn_mfma_f32_16x16x32_bf16(w[0][kk], a, acc[mt][0], 0, 0, 0);
      acc[mt][1] = __builtin_amdgcn_mfma_f32_16x16x32_bf16(w[1][kk], a, acc[mt][1], 0, 0, 0);
    }
  }

  // D[ch][pt]: pt = mt*16 + l16, ch = wv*32 + nt*16 + lk8*4 + i
#pragma unroll
  for (int nt = 0; nt < 2; ++nt) {
    const int ch0 = wv * 32 + nt * 16 + lk8 * 4;
    const f32x4 bv = *(const f32x4*)&bias[ch0];
#pragma unroll
    for (int mt = 0; mt < 4; ++mt) {
      const int pt = mt * 16 + l16;
      short4v pk;
#pragma unroll
      for (int i = 0; i < 4; ++i)
        pk[i] = (short)f2bf(fmaxf(acc[mt][nt][i] + bv[i], 0.0f));
      *(short4v*)&dst[pt][ch0] = pk;   // 8B aligned
    }
  }
}

template <bool TR>
__global__ __launch_bounds__(TPB, 4) void nerf_fused(
    const float* __restrict__ uv,
    const float* __restrict__ W_in, const float* __restrict__ b_in,
    const float* __restrict__ W_h0r, const float* __restrict__ b_h0,
    const float* __restrict__ W_h1r, const float* __restrict__ b_h1,
    const float* __restrict__ W_out, const float* __restrict__ b_out,
    const unsigned short* __restrict__ T0,
    const unsigned short* __restrict__ T1,
    const unsigned short* __restrict__ Wo_t,
    float* __restrict__ out) {
  __shared__ unsigned short hA[MT][ROWE];
  __shared__ unsigned short hB[MT][ROWE];

  const int tid = threadIdx.x;
  const long n0 = (long)blockIdx.x * MT;
  const int wv = tid >> 6, ln = tid & 63;
  const int l16 = ln & 15, lk8 = ln >> 4;

  // issue gemm0 weight prefetch FIRST; clobber pins issue before layer 0
  short8 w[2][8];
  load_w<TR>(w, T0, W_h0r, wv, l16, lk8);
  asm volatile("" ::: "memory");

  { // ---- layer 0: enc=[cos u, cos v, sin u, sin v] -> relu(enc@W_in+b_in)
    const int p = tid >> 3;
    const int t7 = tid & 7;
    const float u = uv[(n0 + p) * 2 + 0];
    const float v = uv[(n0 + p) * 2 + 1];
    const float e0 = __cosf(u), e1 = __cosf(v), e2 = __sinf(u), e3 = __sinf(v);
#pragma unroll
    for (int j = 0; j < 8; ++j) {
      const int c = t7 * 4 + j * 32;
      const f32x4 w0 = *(const f32x4*)&W_in[0 * CCH + c];
      const f32x4 w1 = *(const f32x4*)&W_in[1 * CCH + c];
      const f32x4 w2 = *(const f32x4*)&W_in[2 * CCH + c];
      const f32x4 w3 = *(const f32x4*)&W_in[3 * CCH + c];
      const f32x4 bb = *(const f32x4*)&b_in[c];
      short4v pk;
#pragma unroll
      for (int i = 0; i < 4; ++i) {
        const float x = bb[i] + e0 * w0[i] + e1 * w1[i] + e2 * w2[i] + e3 * w3[i];
        pk[i] = (short)f2bf(fmaxf(x, 0.0f));
      }
      *(short4v*)&hA[p][c] = pk;
    }
  }
  __syncthreads();

  layer_mfma(hA, hB, w, b_h0, wv, l16, lk8);      // h0 -> h1 (consumes w)
  load_w<TR>(w, T1, W_h1r, wv, l16, lk8);         // refill; in flight over sync
  asm volatile("" ::: "memory");
  __syncthreads();
  layer_mfma(hB, hA, w, b_h1, wv, l16, lk8);      // h1 -> h2
  __syncthreads();

  // ---- output layer via MFMA: D = Wo(3x256,zero-pad to 16) @ h2^T ----
  if (wv < 4) {                                   // wave wv owns points wv*16..+15
    f32x4 acc = (f32x4){0.f, 0.f, 0.f, 0.f};
#pragma unroll
    for (int kk = 0; kk < 8; ++kk) {
      const int k = kk * 32 + lk8 * 8;
      short8 wo;
      if constexpr (TR) {
        wo = *(const short8*)&Wo_t[l16 * CCH + k];
      } else {
#pragma unroll
        for (int j = 0; j < 8; ++j)
          wo[j] = (l16 < 3) ? (short)f2bf(W_out[(k + j) * 3 + l16]) : (short)0;
      }
      const short8 hb = *(const short8*)&hA[wv * 16 + l16][k];
      acc = __builtin_amdgcn_mfma_f32_16x16x32_bf16(wo, hb, acc, 0, 0, 0);
    }
    // D: col=l16=point, row=lk8*4+i=output j; only lk8==0, j<3 are real
    if (lk8 == 0) {
      const long pt = n0 + wv * 16 + l16;
#pragma unroll
      for (int i = 0; i < 3; ++i)
        out[pt * 3 + i] = 1.f / (1.f + __expf(-(acc[i] + b_out[i])));
    }
  }
}

extern "C" void kernel_launch(void* const* d_in, const int* in_sizes, int n_in,
                              void* d_out, int out_size, void* d_ws, size_t ws_size,
                              hipStream_t stream) {
  const float* uv    = (const float*)d_in[0];
  const float* W_in  = (const float*)d_in[1];
  const float* b_in  = (const float*)d_in[2];
  const float* W_h0  = (const float*)d_in[3];
  const float* b_h0  = (const float*)d_in[4];
  const float* W_h1  = (const float*)d_in[5];
  const float* b_h1  = (const float*)d_in[6];
  const float* W_out = (const float*)d_in[7];
  const float* b_out = (const float*)d_in[8];

  const int N = in_sizes[0] / 2;                    // 524288
  const size_t t_bytes =
      (size_t)(2 * CCH * CCH + 16 * CCH) * sizeof(unsigned short);  // 264 KiB

  if (ws_size >= t_bytes) {
    unsigned short* T0 = (unsigned short*)d_ws;     // 256*256 bf16
    unsigned short* T1 = T0 + CCH * CCH;
    unsigned short* Wo = T1 + CCH * CCH;            // 16*256 bf16
    transpose_w<<<dim3(8, 8, 2), dim3(32, 8), 0, stream>>>(W_h0, W_h1, T0, T1);
    prep_wo<<<1, CCH, 0, stream>>>(W_out, Wo);
    nerf_fused<true><<<dim3(N / MT), dim3(TPB), 0, stream>>>(
        uv, W_in, b_in, W_h0, b_h0, W_h1, b_h1, W_out, b_out, T0, T1, Wo,
        (float*)d_out);
  } else {
    nerf_fused<false><<<dim3(N / MT), dim3(TPB), 0, stream>>>(
        uv, W_in, b_in, W_h0, b_h0, W_h1, b_h1, W_out, b_out,
        (const unsigned short*)nullptr, (const unsigned short*)nullptr,
        (const unsigned short*)nullptr, (float*)d_out);
  }
}